// Round 1
// 346.956 us; speedup vs baseline: 1.0160x; 1.0160x over previous
//
#include <hip/hip_runtime.h>
#include <stdint.h>

// BitLinear (BitNet b1.58 fake-quant) on gfx950.
// y = (int8 qx @ ternary qw^T) * alpha[m] * wdq + bias[n]; int32 accum exact.
// Round 3: double-buffered stage-ahead K-loop (1 barrier/K-step, load latency
// hidden under MFMA), bijective XCD-chunked tile swizzle (A fetched once per
// XCD, B L2-resident).

typedef __attribute__((ext_vector_type(4))) int int4v;
typedef __attribute__((ext_vector_type(16))) int int16v;

#define DIN   512
#define DOUT  2048
#define NTOK  32768          // 8 * 4096
#define WELEM (DOUT * DIN)   // 1048576

// ---------------- async global->LDS (width 16) ----------------
__device__ __forceinline__ void async16(const void* g, void* l) {
  __builtin_amdgcn_global_load_lds(
      reinterpret_cast<const __attribute__((address_space(1))) void*>(
          reinterpret_cast<uintptr_t>(g)),
      reinterpret_cast<__attribute__((address_space(3))) void*>(
          reinterpret_cast<uintptr_t>(l)),
      16u, 0, 0u);
}

// ---------------- kernel 1: sum(|w|) partials (deterministic) ----------------
__global__ void wabs_reduce(const float* __restrict__ w, double* __restrict__ partials) {
  __shared__ double red[256];
  const int t = threadIdx.x;
  const float4* w4 = (const float4*)w;
  const int base = blockIdx.x * 1024;   // 256 blocks * 1024 float4 = 262144 float4
  double s = 0.0;
#pragma unroll
  for (int k = 0; k < 4; ++k) {
    float4 v = w4[base + k * 256 + t];
    s += (double)fabsf(v.x) + (double)fabsf(v.y) + (double)fabsf(v.z) + (double)fabsf(v.w);
  }
  red[t] = s;
  __syncthreads();
  for (int o = 128; o > 0; o >>= 1) {
    if (t < o) red[t] += red[t + o];
    __syncthreads();
  }
  if (t == 0) partials[blockIdx.x] = red[0];
}

// ---------------- kernel 2: finalize weight scale ----------------
__global__ void wscale_fin(const double* __restrict__ partials, float* __restrict__ scales) {
  __shared__ double red[256];
  const int t = threadIdx.x;
  red[t] = partials[t];
  __syncthreads();
  for (int o = 128; o > 0; o >>= 1) {
    if (t < o) red[t] += red[t + o];
    __syncthreads();
  }
  if (t == 0) {
    const float mean = (float)(red[0] * (1.0 / (double)WELEM));
    const float me   = fmaxf(mean, 1e-6f);
    const float sc   = 1.0f / me;    // scale used for quantization (matches ref)
    scales[0] = sc;
    scales[1] = 1.0f / sc;           // wdq: exactly ref's q/scale for q=+-1
  }
}

// ---------------- kernel 3: ternary weight quant ----------------
__global__ void wquant(const float* __restrict__ w, const float* __restrict__ scales,
                       char* __restrict__ qw) {
  const float s = scales[0];
  const int idx = blockIdx.x * 256 + threadIdx.x;   // float4 index, 262144 total (1024 blocks)
  const float4 v = ((const float4*)w)[idx];
  union { signed char c[4]; int u; } pk;
  pk.c[0] = (signed char)(int)fmaxf(-1.f, fminf(1.f, rintf(v.x * s)));
  pk.c[1] = (signed char)(int)fmaxf(-1.f, fminf(1.f, rintf(v.y * s)));
  pk.c[2] = (signed char)(int)fmaxf(-1.f, fminf(1.f, rintf(v.z * s)));
  pk.c[3] = (signed char)(int)fmaxf(-1.f, fminf(1.f, rintf(v.w * s)));
  ((int*)qw)[idx] = pk.u;
}

// ---------------- kernel 4: per-token int8 activation quant (coalesced) ------
__device__ __forceinline__ signed char q1(float x, float s) {
  float r = rintf(x * s);                 // round half-to-even == jnp.round
  r = fminf(127.f, fmaxf(-128.f, r));
  return (signed char)(int)r;
}

__global__ void act_quant(const float* __restrict__ x, char* __restrict__ qx,
                          float* __restrict__ alpha) {
  const int t = threadIdx.x;
  const int lane = t & 63;
  const int wid = t >> 6;
  const int token = blockIdx.x * 4 + wid;   // 8192 blocks * 4 tokens
  const float4* xr = (const float4*)(x + (size_t)token * DIN);
  const float4 v0 = xr[lane];        // elements lane*4 .. +3
  const float4 v1 = xr[64 + lane];   // elements 256+lane*4 .. +3
  float am = fmaxf(fmaxf(fmaxf(fabsf(v0.x), fabsf(v0.y)), fmaxf(fabsf(v0.z), fabsf(v0.w))),
                   fmaxf(fmaxf(fabsf(v1.x), fabsf(v1.y)), fmaxf(fabsf(v1.z), fabsf(v1.w))));
#pragma unroll
  for (int o = 32; o > 0; o >>= 1) am = fmaxf(am, __shfl_xor(am, o, 64));
  am = fmaxf(am, 1e-6f);
  const float scale = 127.0f / am;
  union { signed char c[4]; int u; } p0, p1;
  p0.c[0] = q1(v0.x, scale);  p0.c[1] = q1(v0.y, scale);
  p0.c[2] = q1(v0.z, scale);  p0.c[3] = q1(v0.w, scale);
  p1.c[0] = q1(v1.x, scale);  p1.c[1] = q1(v1.y, scale);
  p1.c[2] = q1(v1.z, scale);  p1.c[3] = q1(v1.w, scale);
  int* qrow = (int*)(qx + (size_t)token * DIN);
  qrow[lane]      = p0.u;
  qrow[64 + lane] = p1.u;
  if (lane == 0) alpha[token] = 1.0f / scale;
}

// ---------------- kernel 5: int8 MFMA GEMM, 128x128 tile, BK=64, 32x32x32 ----
// A = qx [32768 x 512] int8 row-major, B = qw [2048 x 512] int8 row-major.
// LDS swizzle: physical 16B chunk p holds logical chunk p ^ ((row>>1)&3);
// conflict-free per 8-lane phase for both staging and fragment reads.
// Pipeline: double-buffered LDS; per K-step: stage(next)->ds_read+MFMA(cur)->
// barrier (the barrier's vmcnt(0) drain lands AFTER ~900 cyc of compute, so
// global-load latency is hidden instead of exposed 8x per block).
__global__ __launch_bounds__(256, 3) void gemm_i8(
    const char* __restrict__ qx, const char* __restrict__ qw,
    const float* __restrict__ alpha, const float* __restrict__ bias,
    const float* __restrict__ scales, float* __restrict__ out) {
  __shared__ __align__(16) char As[2 * 128 * 64];   // 16 KB = 2 buffers x 8 KB
  __shared__ __align__(16) char Bs[2 * 128 * 64];
  const int t = threadIdx.x;
  const int lane = t & 63;
  const int wid = t >> 6;
  const int wm = wid & 1;
  const int wn = wid >> 1;

  // Bijective XCD-chunked remap (8 XCDs, nwg = 4096, 4096 % 8 == 0).
  // Hardware dispatches linear block b round-robin to XCD b%8; remap so each
  // XCD owns a contiguous tile range, x-fastest within the chunk: each
  // A-panel (y) is then consumed entirely by ONE XCD (16 consecutive tiles),
  // and B (1 MB) stays resident in that XCD's 4 MB L2.
  const int lin = blockIdx.y * 16 + blockIdx.x;
  const int f   = (lin & 7) * 512 + (lin >> 3);   // tile index, bijective
  const int m0  = (f >> 4) * 128;                 // 256 y-panels
  const int n0  = (f & 15) * 128;                 // 16 x-tiles (fastest)

  // staging: thread t -> row0 = t>>2 (second issue adds 64 rows), phys chunk t&3
  const int row0 = t >> 2;
  const int p0 = t & 3;
  const int kq = (p0 ^ ((row0 >> 1) & 3)) * 16;   // swizzled k-byte offset
  const char* ga0 = qx + (size_t)(m0 + row0) * DIN + kq;
  const char* ga1 = qx + (size_t)(m0 + row0 + 64) * DIN + kq;
  const char* gb0 = qw + (size_t)(n0 + row0) * DIN + kq;
  const char* gb1 = qw + (size_t)(n0 + row0 + 64) * DIN + kq;
  char* la0 = As + wid * 1024;           // wave-uniform LDS bases (lane*16 added by HW)
  char* la1 = As + 4096 + wid * 1024;
  char* lb0 = Bs + wid * 1024;
  char* lb1 = Bs + 4096 + wid * 1024;

  // fragment pointers: 32x32x32 A-frag: m = lane&31, k = (lane>>5)*16 + khalf*32
  const int r5 = lane & 31;
  const int kg = lane >> 5;
  const int xorv = (r5 >> 1) & 3;                  // row-swizzle bits (tile bases %8==0)
  const int pa_off = (wm * 64 + r5) * 64;
  const int pb_off = (wn * 64 + r5) * 64;
  int off[2];                                      // byte offset per k-half
#pragma unroll
  for (int h = 0; h < 2; ++h) off[h] = ((kg + 2 * h) ^ xorv) * 16;

  int16v acc[2][2] = {};

  // ---- prologue: stage K-chunk 0 into buffer 0 ----
  async16(ga0, la0);
  async16(ga1, la1);
  async16(gb0, lb0);
  async16(gb1, lb1);
  __syncthreads();   // drains vmcnt(0): only exposed load latency in the kernel

  int buf = 0;
#pragma unroll
  for (int kk = 64; kk < DIN; kk += 64) {
    // stage NEXT chunk into the other buffer (latency hidden under compute)
    const int nboff = (buf ^ 1) * 8192;
    async16(ga0 + kk, la0 + nboff);
    async16(ga1 + kk, la1 + nboff);
    async16(gb0 + kk, lb0 + nboff);
    async16(gb1 + kk, lb1 + nboff);

    // compute on current buffer
    const char* pa = As + buf * 8192 + pa_off;
    const char* pb = Bs + buf * 8192 + pb_off;
    int4v a[2][2], b[2][2];                        // [mblock][khalf]
#pragma unroll
    for (int i = 0; i < 2; ++i)
#pragma unroll
      for (int h = 0; h < 2; ++h) {
        a[i][h] = *(const int4v*)(pa + i * 2048 + off[h]);
        b[i][h] = *(const int4v*)(pb + i * 2048 + off[h]);
      }
#pragma unroll
    for (int i = 0; i < 2; ++i)
#pragma unroll
      for (int j = 0; j < 2; ++j) {
        acc[i][j] = __builtin_amdgcn_mfma_i32_32x32x32_i8(a[i][0], b[j][0], acc[i][j], 0, 0, 0);
        acc[i][j] = __builtin_amdgcn_mfma_i32_32x32x32_i8(a[i][1], b[j][1], acc[i][j], 0, 0, 0);
      }
    // one barrier per K-step: (a) all waves' ds_reads of buf done before next
    // iter overwrites it; (b) implicit vmcnt(0) drain of the stage issued
    // ABOVE, which has had the whole compute phase to land.
    __syncthreads();
    buf ^= 1;
  }

  // ---- epilogue compute: last K-chunk (already staged & drained) ----
  {
    const char* pa = As + buf * 8192 + pa_off;
    const char* pb = Bs + buf * 8192 + pb_off;
    int4v a[2][2], b[2][2];
#pragma unroll
    for (int i = 0; i < 2; ++i)
#pragma unroll
      for (int h = 0; h < 2; ++h) {
        a[i][h] = *(const int4v*)(pa + i * 2048 + off[h]);
        b[i][h] = *(const int4v*)(pb + i * 2048 + off[h]);
      }
#pragma unroll
    for (int i = 0; i < 2; ++i)
#pragma unroll
      for (int j = 0; j < 2; ++j) {
        acc[i][j] = __builtin_amdgcn_mfma_i32_32x32x32_i8(a[i][0], b[j][0], acc[i][j], 0, 0, 0);
        acc[i][j] = __builtin_amdgcn_mfma_i32_32x32x32_i8(a[i][1], b[j][1], acc[i][j], 0, 0, 0);
      }
  }

  // epilogue: C/D 32x32 layout col=lane&31, row=(reg&3)+8*(reg>>2)+4*(lane>>5)
  const float wdq = scales[1];
  const int h4 = (lane >> 5) * 4;
  const int col0 = n0 + wn * 64 + r5;
  const float bb0 = bias[col0];
  const float bb1 = bias[col0 + 32];
#pragma unroll
  for (int i = 0; i < 2; ++i) {
    const int rb = m0 + wm * 64 + i * 32 + h4;
#pragma unroll
    for (int rg = 0; rg < 4; ++rg) {               // reg>>2
      const float4 a4 = *(const float4*)(alpha + rb + rg * 8);  // rows rb+rg*8 .. +3
#pragma unroll
      for (int rl = 0; rl < 4; ++rl) {             // reg&3
        const int row = rb + rg * 8 + rl;
        const float s = ((const float*)&a4)[rl] * wdq;
        const int reg = rg * 4 + rl;
        float* o = out + (size_t)row * DOUT + col0;
        o[0]  = (float)acc[i][0][reg] * s + bb0;   // lanes 0-31 + 32-63: 2x128B segments
        o[32] = (float)acc[i][1][reg] * s + bb1;
      }
    }
  }
}

// ---------------- launch ----------------
extern "C" void kernel_launch(void* const* d_in, const int* in_sizes, int n_in,
                              void* d_out, int out_size, void* d_ws, size_t ws_size,
                              hipStream_t stream) {
  const float* x    = (const float*)d_in[0];
  const float* w    = (const float*)d_in[1];
  const float* bias = (const float*)d_in[2];
  float* out = (float*)d_out;

  char* ws = (char*)d_ws;
  double* partials = (double*)ws;             //    0 .. 2048   (256 doubles)
  float*  scales   = (float*)(ws + 2048);     // [0]=scale_w, [1]=wdq
  float*  alpha    = (float*)(ws + 4096);     // 32768 floats  -> 135168
  char*   qw       = ws + 135168;             // 1 MB          -> 1183744
  char*   qx       = ws + 1183744;            // 16 MB         -> 17960960 total

  wabs_reduce<<<256, 256, 0, stream>>>(w, partials);
  wscale_fin<<<1, 256, 0, stream>>>(partials, scales);
  wquant<<<1024, 256, 0, stream>>>(w, scales, qw);
  act_quant<<<8192, 256, 0, stream>>>(x, qx, alpha);
  gemm_i8<<<dim3(16, 256), 256, 0, stream>>>(qx, qw, alpha, bias, scales, out);
}